// Round 1
// baseline (951.081 us; speedup 1.0000x reference)
//
#include <hip/hip_runtime.h>
#include <hip/hip_bf16.h>

#define D_IN 512
#define NEXP 32
#define HID 16
#define NT 34            // 544 cols / 16
#define KSTEPS 16        // 512 / 32
#define BM 64
#define BATCH 262144

typedef __attribute__((ext_vector_type(8))) short bfrag;   // 8 x bf16
typedef __attribute__((ext_vector_type(4))) float f32x4;

__device__ inline ushort f2bf(float f) {
  uint32_t u = __float_as_uint(f);
  u += 0x7fffu + ((u >> 16) & 1u);      // RNE, finite inputs
  return (ushort)(u >> 16);
}

__device__ inline float red16sum(float v) {
  v += __shfl_xor(v, 1); v += __shfl_xor(v, 2);
  v += __shfl_xor(v, 4); v += __shfl_xor(v, 8);
  return v;
}
__device__ inline float red16max(float v) {
  v = fmaxf(v, __shfl_xor(v, 1)); v = fmaxf(v, __shfl_xor(v, 2));
  v = fmaxf(v, __shfl_xor(v, 4)); v = fmaxf(v, __shfl_xor(v, 8));
  return v;
}
__device__ inline float gelu(float v) {
  return 0.5f * v * (1.0f + erff(v * 0.70710678118654752f));
}

__device__ inline void gload_lds16(const ushort* g, ushort* l) {
  __builtin_amdgcn_global_load_lds(
      (const __attribute__((address_space(1))) void*)g,
      (__attribute__((address_space(3))) void*)l, 16, 0, 0);
}

// ---- Pre-pack Wcat[512,544] (gating cols 0..31, then expert e hid j at col 32+e*16+j)
// into bf16 MFMA B-fragment order: P[ks][t][lane][j] ; element j of lane l, tile t, kstep ks
// = Wcat[k = ks*32 + (l>>4)*8 + j][n = t*16 + (l&15)]
__global__ void prepack_kernel(const float* __restrict__ Wg,
                               const float* __restrict__ W1,
                               ushort* __restrict__ P) {
  int tid = blockIdx.x * 256 + threadIdx.x;
  const int total = KSTEPS * NT * 64;
  if (tid >= total) return;
  int l  = tid & 63;
  int t  = (tid >> 6) % NT;
  int ks = tid / (NT * 64);
  int n  = t * 16 + (l & 15);
  int kb = ks * 32 + (l >> 4) * 8;
  __align__(16) ushort v[8];
#pragma unroll
  for (int j = 0; j < 8; ++j) {
    int k = kb + j;
    float w;
    if (n < NEXP) {
      w = Wg[n * D_IN + k];
    } else {
      int e = (n - 32) >> 4, h = (n - 32) & 15;
      w = W1[(e * D_IN + k) * HID + h];
    }
    v[j] = f2bf(w);
  }
  *reinterpret_cast<int4*>(P + (size_t)tid * 8) = *reinterpret_cast<const int4*>(v);
}

// ---- Main fused kernel: 256 thr = 4 waves (wm in {0,1} x wn in {0,1}); BM=64 rows/block.
// Wave tile: 32 rows x 272 cols (2 M-frags x 17 N-tiles, 16x16x32 bf16 MFMA).
__global__ __launch_bounds__(256, 2)
void moe_kernel(const float* __restrict__ x, const ushort* __restrict__ P,
                const float* __restrict__ b1, const float* __restrict__ W2,
                const float* __restrict__ b2, float* __restrict__ out) {
  __shared__ __align__(16) ushort Alds[BM * 32];     // [row][slot(4)][8 bf16], slot XOR-swizzled
  __shared__ __align__(16) ushort Blds[NT * 512];    // tile t: 64 lanes x 8 bf16, linear
  __shared__ float epi[BM * 20];                     // per row: ghat[16..31], ghat15, s, p0

  const int tid = threadIdx.x;
  const int l = tid & 63;
  const int wid = tid >> 6;
  const int wm = wid >> 1, wn = wid & 1;
  const int lane16 = l & 15, lg = l >> 4;
  const size_t rowBase = (size_t)blockIdx.x * BM;

  f32x4 acc[2][17];
#pragma unroll
  for (int f = 0; f < 2; ++f)
#pragma unroll
    for (int t = 0; t < 17; ++t) acc[f][t] = (f32x4){0.f, 0.f, 0.f, 0.f};

  // A-staging assignment: each thread owns (row, chunk) ; chunk = 8 consecutive k
  const int srow = tid >> 2, sch = tid & 3;
  const int sslot = sch ^ ((srow >> 1) & 3);
  const float* xsrc = x + (rowBase + srow) * D_IN + sch * 8;
  ushort* adst = Alds + srow * 32 + sslot * 8;

  for (int ks = 0; ks < KSTEPS; ++ks) {
    // stage A: fp32 -> bf16 -> LDS
    const float4 f0 = *reinterpret_cast<const float4*>(xsrc + ks * 32);
    const float4 f1 = *reinterpret_cast<const float4*>(xsrc + ks * 32 + 4);
    __align__(16) ushort av[8];
    av[0] = f2bf(f0.x); av[1] = f2bf(f0.y); av[2] = f2bf(f0.z); av[3] = f2bf(f0.w);
    av[4] = f2bf(f1.x); av[5] = f2bf(f1.y); av[6] = f2bf(f1.z); av[7] = f2bf(f1.w);
    *reinterpret_cast<int4*>(adst) = *reinterpret_cast<const int4*>(av);
    // stage B: prepacked bf16, direct global->LDS (linear layout, 1 KiB per tile)
    for (int tg = wid; tg < NT; tg += 4)
      gload_lds16(P + ((size_t)(ks * NT + tg) * 64 + l) * 8, Blds + tg * 512);
    __syncthreads();

    const int r0 = wm * 32 + lane16;
    const bfrag a0 = *reinterpret_cast<const bfrag*>(Alds + r0 * 32 + ((lg ^ ((r0 >> 1) & 3)) * 8));
    const int r1 = r0 + 16;
    const bfrag a1 = *reinterpret_cast<const bfrag*>(Alds + r1 * 32 + ((lg ^ ((r1 >> 1) & 3)) * 8));
#pragma unroll
    for (int t = 0; t < 17; ++t) {
      const bfrag b = *reinterpret_cast<const bfrag*>(Blds + (wn * 17 + t) * 512 + l * 8);
      acc[0][t] = __builtin_amdgcn_mfma_f32_16x16x32_bf16(a0, b, acc[0][t], 0, 0, 0);
      acc[1][t] = __builtin_amdgcn_mfma_f32_16x16x32_bf16(a1, b, acc[1][t], 0, 0, 0);
    }
    __syncthreads();
  }

  // ---- epilogue. C/D layout: col = lane&15, row = (lane>>4)*4 + reg  [m89]
  // wn0 tiles: t=0,1 gating (e = lane16, 16+lane16); t=2..16 experts 0..14
  // wn1 tiles: t=0..16 experts 15..31
  if (wn == 0) {
    float e0a[2][4], e1a[2][4], sa[2][4], pac[2][4];
#pragma unroll
    for (int f = 0; f < 2; ++f)
#pragma unroll
      for (int r = 0; r < 4; ++r) {
        float g0 = acc[f][0][r], g1 = acc[f][1][r];
        float mx = red16max(fmaxf(g0, g1));
        float e0 = __expf(g0 - mx), e1 = __expf(g1 - mx);
        sa[f][r] = red16sum(e0 + e1);
        e0a[f][r] = e0; e1a[f][r] = e1; pac[f][r] = 0.f;
      }
#pragma unroll
    for (int t = 2; t < 17; ++t) {
      const int e = t - 2;
      const float b1v = b1[e * HID + lane16];
      const float w2v = W2[e * HID + lane16];
      const float b2v = b2[e];
#pragma unroll
      for (int f = 0; f < 2; ++f)
#pragma unroll
        for (int r = 0; r < 4; ++r) {
          float o = red16sum(gelu(acc[f][t][r] + b1v) * w2v) + b2v;
          if (lane16 == e) pac[f][r] += o * e0a[f][r];
        }
    }
#pragma unroll
    for (int f = 0; f < 2; ++f)
#pragma unroll
      for (int r = 0; r < 4; ++r) {
        float p0 = red16sum(pac[f][r]);
        int rowl = wm * 32 + f * 16 + lg * 4 + r;
        epi[rowl * 20 + lane16] = e1a[f][r];                      // ghat[16+lane16]
        if (lane16 == 15) epi[rowl * 20 + 16] = e0a[f][r];        // ghat[15]
        if (lane16 == 0) { epi[rowl * 20 + 17] = sa[f][r]; epi[rowl * 20 + 18] = p0; }
      }
  }
  __syncthreads();
  if (wn == 1) {
    float ghat[2][4], g15[2][4], sv[2][4], p0v[2][4], pac[2][4];
#pragma unroll
    for (int f = 0; f < 2; ++f)
#pragma unroll
      for (int r = 0; r < 4; ++r) {
        int rowl = wm * 32 + f * 16 + lg * 4 + r;
        ghat[f][r] = epi[rowl * 20 + lane16];
        g15[f][r]  = epi[rowl * 20 + 16];
        sv[f][r]   = epi[rowl * 20 + 17];
        p0v[f][r]  = epi[rowl * 20 + 18];
        pac[f][r] = 0.f;
      }
#pragma unroll
    for (int t = 0; t < 17; ++t) {
      const int e = 15 + t;
      const float b1v = b1[e * HID + lane16];
      const float w2v = W2[e * HID + lane16];
      const float b2v = b2[e];
#pragma unroll
      for (int f = 0; f < 2; ++f)
#pragma unroll
        for (int r = 0; r < 4; ++r) {
          float o = red16sum(gelu(acc[f][t][r] + b1v) * w2v) + b2v;
          if (e == 15) {
            if (lane16 == 15) pac[f][r] += o * g15[f][r];
          } else if (lane16 == (e - 16)) {
            pac[f][r] += o * ghat[f][r];
          }
        }
    }
#pragma unroll
    for (int f = 0; f < 2; ++f)
#pragma unroll
      for (int r = 0; r < 4; ++r) {
        float p1 = red16sum(pac[f][r]);
        int rowl = wm * 32 + f * 16 + lg * 4 + r;
        if (lane16 == 0) out[rowBase + rowl] = (p0v[f][r] + p1) / sv[f][r];
      }
  }
}

extern "C" void kernel_launch(void* const* d_in, const int* in_sizes, int n_in,
                              void* d_out, int out_size, void* d_ws, size_t ws_size,
                              hipStream_t stream) {
  const float* x  = (const float*)d_in[0];
  const float* Wg = (const float*)d_in[1];
  const float* W1 = (const float*)d_in[2];
  const float* b1 = (const float*)d_in[3];
  const float* W2 = (const float*)d_in[4];
  const float* b2 = (const float*)d_in[5];
  float* out = (float*)d_out;
  ushort* P = (ushort*)d_ws;   // needs 16*34*64*8*2 = 557,056 B

  hipLaunchKernelGGL(prepack_kernel, dim3((KSTEPS * NT * 64 + 255) / 256), dim3(256),
                     0, stream, Wg, W1, P);
  hipLaunchKernelGGL(moe_kernel, dim3(BATCH / BM), dim3(256),
                     0, stream, x, P, b1, W2, b2, out);
}

// Round 2
// 550.949 us; speedup vs baseline: 1.7263x; 1.7263x over previous
//
#include <hip/hip_runtime.h>
#include <hip/hip_bf16.h>

#define D_IN 512
#define NEXP 32
#define HID 16
#define NT 34            // 544 cols / 16
#define KSTEPS 16        // 512 / 32
#define BM 64
#define BATCH 262144

typedef __attribute__((ext_vector_type(8))) short bfrag;   // 8 x bf16
typedef __attribute__((ext_vector_type(4))) float f32x4;

__device__ inline ushort f2bf(float f) {
  uint32_t u = __float_as_uint(f);
  u += 0x7fffu + ((u >> 16) & 1u);      // RNE, finite inputs
  return (ushort)(u >> 16);
}

// pack 8 fp32 -> 8 bf16 (RNE) with v_cvt_pk_bf16_f32
__device__ inline bfrag cvt8(const float4 a, const float4 b) {
  union { bfrag v; uint u[4]; } r;
  asm("v_cvt_pk_bf16_f32 %0, %1, %2" : "=v"(r.u[0]) : "v"(a.x), "v"(a.y));
  asm("v_cvt_pk_bf16_f32 %0, %1, %2" : "=v"(r.u[1]) : "v"(a.z), "v"(a.w));
  asm("v_cvt_pk_bf16_f32 %0, %1, %2" : "=v"(r.u[2]) : "v"(b.x), "v"(b.y));
  asm("v_cvt_pk_bf16_f32 %0, %1, %2" : "=v"(r.u[3]) : "v"(b.z), "v"(b.w));
  return r.v;
}

// tanh-form GELU: 0.5x(1+tanh(0.79788456(x+0.044715x^3))), exp-based
__device__ inline float gelu_t(float v) {
  float t = 0.7978845608028654f * fmaf(0.044715f * v * v, v, v);
  t = fminf(fmaxf(t, -9.f), 9.f);
  float e = __expf(-2.f * t);
  float th = (1.f - e) * __builtin_amdgcn_rcpf(1.f + e);
  return 0.5f * v * (1.f + th);
}

// ---- Pre-pack Wcat[512,544] (gating cols 0..31, then expert e hid j at col 32+e*16+j)
// into bf16 MFMA fragment order: P[ks][t][lane][j] = Wcat[k=ks*32+(l>>4)*8+j][n=t*16+(l&15)]
__global__ void prepack_kernel(const float* __restrict__ Wg,
                               const float* __restrict__ W1,
                               ushort* __restrict__ P) {
  int tid = blockIdx.x * 256 + threadIdx.x;
  const int total = KSTEPS * NT * 64;
  if (tid >= total) return;
  int l  = tid & 63;
  int t  = (tid >> 6) % NT;
  int ks = tid / (NT * 64);
  int n  = t * 16 + (l & 15);
  int kb = ks * 32 + (l >> 4) * 8;
  __align__(16) ushort v[8];
#pragma unroll
  for (int j = 0; j < 8; ++j) {
    int k = kb + j;
    float w;
    if (n < NEXP) {
      w = Wg[n * D_IN + k];
    } else {
      int e = (n - 32) >> 4, h = (n - 32) & 15;
      w = W1[(e * D_IN + k) * HID + h];
    }
    v[j] = f2bf(w);
  }
  *reinterpret_cast<int4*>(P + (size_t)tid * 8) = *reinterpret_cast<const int4*>(v);
}

// ---- Main fused kernel, barrier-free GEMM:
// 4 waves (wm x wn = 2x2), BM=64 rows/block. acc = mfma(Wfrag, xfrag) -> C^T:
// C layout per tile: lane&15 = batch row (within 16-row group), (l>>4)*4+r = tile col (h or e).
__global__ __launch_bounds__(256, 2)
void moe_kernel(const float* __restrict__ x, const ushort* __restrict__ P,
                const float* __restrict__ b1, const float* __restrict__ W2,
                const float* __restrict__ b2, float* __restrict__ out) {
  __shared__ float epi_o[NEXP][BM];   // expert outputs per row
  __shared__ float epi_g[NEXP][BM];   // unnormalized gate exp per row
  __shared__ float epi_s[BM];         // softmax denom per row

  const int tid = threadIdx.x;
  const int l = tid & 63;
  const int wid = tid >> 6;
  const int wm = wid >> 1, wn = wid & 1;
  const int lane16 = l & 15, lg = l >> 4;
  const size_t rowBase = (size_t)blockIdx.x * BM;

  f32x4 acc[2][17];
#pragma unroll
  for (int f = 0; f < 2; ++f)
#pragma unroll
    for (int t = 0; t < 17; ++t) acc[f][t] = (f32x4){0.f, 0.f, 0.f, 0.f};

  // x fragment: row = rowBase + wm*32 + f*16 + lane16, k = ks*32 + lg*8 + j
  const float* xp0 = x + (rowBase + wm * 32 + lane16) * D_IN + lg * 8;
  const float* xp1 = xp0 + 16 * D_IN;
  // W fragment: tile tg = wn*17 + t
  const ushort* Pp = P + ((size_t)wn * 17 * 64 + l) * 8;

  for (int ks = 0; ks < KSTEPS; ++ks) {
    const float4 a00 = *reinterpret_cast<const float4*>(xp0 + ks * 32);
    const float4 a01 = *reinterpret_cast<const float4*>(xp0 + ks * 32 + 4);
    const float4 a10 = *reinterpret_cast<const float4*>(xp1 + ks * 32);
    const float4 a11 = *reinterpret_cast<const float4*>(xp1 + ks * 32 + 4);
    const bfrag a0 = cvt8(a00, a01);
    const bfrag a1 = cvt8(a10, a11);
#pragma unroll
    for (int t = 0; t < 17; ++t) {
      const bfrag b = *reinterpret_cast<const bfrag*>(Pp + (size_t)(ks * NT + t) * 512);
      acc[0][t] = __builtin_amdgcn_mfma_f32_16x16x32_bf16(b, a0, acc[0][t], 0, 0, 0);
      acc[1][t] = __builtin_amdgcn_mfma_f32_16x16x32_bf16(b, a1, acc[1][t], 0, 0, 0);
    }
  }

  const int row0 = wm * 32 + lane16;

  if (wn == 0) {
    // gating softmax (tiles 0,1): scores e = t*16 + lg*4 + r for row = row0 + f*16
#pragma unroll
    for (int f = 0; f < 2; ++f) {
      const int row = row0 + f * 16;
      float mx = fmaxf(fmaxf(fmaxf(acc[f][0][0], acc[f][0][1]), fmaxf(acc[f][0][2], acc[f][0][3])),
                       fmaxf(fmaxf(acc[f][1][0], acc[f][1][1]), fmaxf(acc[f][1][2], acc[f][1][3])));
      mx = fmaxf(mx, __shfl_xor(mx, 16));
      mx = fmaxf(mx, __shfl_xor(mx, 32));
      float sum = 0.f;
#pragma unroll
      for (int t = 0; t < 2; ++t)
#pragma unroll
        for (int r = 0; r < 4; ++r) {
          float gh = __expf(acc[f][t][r] - mx);
          sum += gh;
          epi_g[t * 16 + lg * 4 + r][row] = gh;
        }
      sum += __shfl_xor(sum, 16);
      sum += __shfl_xor(sum, 32);
      if (lg == 0) epi_s[row] = sum;
    }
    // experts 0..14 (tiles 2..16): h = lg*4 + r
#pragma unroll
    for (int t = 2; t < 17; ++t) {
      const int e = t - 2;
      const float4 b1v = *reinterpret_cast<const float4*>(b1 + e * HID + lg * 4);
      const float4 w2v = *reinterpret_cast<const float4*>(W2 + e * HID + lg * 4);
      const float b2v = b2[e];
#pragma unroll
      for (int f = 0; f < 2; ++f) {
        float p = gelu_t(acc[f][t][0] + b1v.x) * w2v.x;
        p = fmaf(gelu_t(acc[f][t][1] + b1v.y), w2v.y, p);
        p = fmaf(gelu_t(acc[f][t][2] + b1v.z), w2v.z, p);
        p = fmaf(gelu_t(acc[f][t][3] + b1v.w), w2v.w, p);
        p += __shfl_xor(p, 16);
        p += __shfl_xor(p, 32);
        if (lg == (t & 3)) epi_o[e][row0 + f * 16] = p + b2v;
      }
    }
  } else {
    // experts 15..31 (tiles 0..16)
#pragma unroll
    for (int t = 0; t < 17; ++t) {
      const int e = t + 15;
      const float4 b1v = *reinterpret_cast<const float4*>(b1 + e * HID + lg * 4);
      const float4 w2v = *reinterpret_cast<const float4*>(W2 + e * HID + lg * 4);
      const float b2v = b2[e];
#pragma unroll
      for (int f = 0; f < 2; ++f) {
        float p = gelu_t(acc[f][t][0] + b1v.x) * w2v.x;
        p = fmaf(gelu_t(acc[f][t][1] + b1v.y), w2v.y, p);
        p = fmaf(gelu_t(acc[f][t][2] + b1v.z), w2v.z, p);
        p = fmaf(gelu_t(acc[f][t][3] + b1v.w), w2v.w, p);
        p += __shfl_xor(p, 16);
        p += __shfl_xor(p, 32);
        if (lg == (t & 3)) epi_o[e][row0 + f * 16] = p + b2v;
      }
    }
  }

  __syncthreads();
  if (tid < BM) {
    float a = 0.f;
#pragma unroll
    for (int e = 0; e < NEXP; ++e)
      a = fmaf(epi_o[e][tid], epi_g[e][tid], a);
    out[rowBase + tid] = a / epi_s[tid];
  }
}

extern "C" void kernel_launch(void* const* d_in, const int* in_sizes, int n_in,
                              void* d_out, int out_size, void* d_ws, size_t ws_size,
                              hipStream_t stream) {
  const float* x  = (const float*)d_in[0];
  const float* Wg = (const float*)d_in[1];
  const float* W1 = (const float*)d_in[2];
  const float* b1 = (const float*)d_in[3];
  const float* W2 = (const float*)d_in[4];
  const float* b2 = (const float*)d_in[5];
  float* out = (float*)d_out;
  ushort* P = (ushort*)d_ws;   // 16*34*64*8*2 = 557,056 B

  hipLaunchKernelGGL(prepack_kernel, dim3((KSTEPS * NT * 64 + 255) / 256), dim3(256),
                     0, stream, Wg, W1, P);
  hipLaunchKernelGGL(moe_kernel, dim3(BATCH / BM), dim3(256),
                     0, stream, x, P, b1, W2, b2, out);
}

// Round 3
// 329.577 us; speedup vs baseline: 2.8858x; 1.6717x over previous
//
#include <hip/hip_runtime.h>
#include <hip/hip_bf16.h>

#define D_IN 512
#define NEXP 32
#define HID 16
#define NT 34            // 544 cols / 16
#define KSTEPS 16        // 512 / 32
#define BM 128
#define NW 8             // waves per block
#define BATCH 262144

typedef __attribute__((ext_vector_type(8))) short bfrag;   // 8 x bf16
typedef __attribute__((ext_vector_type(4))) float f32x4;

__device__ inline ushort f2bf(float f) {
  uint32_t u = __float_as_uint(f);
  u += 0x7fffu + ((u >> 16) & 1u);      // RNE, finite inputs
  return (ushort)(u >> 16);
}

// pack 8 fp32 -> 8 bf16 (RNE) with v_cvt_pk_bf16_f32
__device__ inline bfrag cvt8(const float4 a, const float4 b) {
  union { bfrag v; uint u[4]; } r;
  asm("v_cvt_pk_bf16_f32 %0, %1, %2" : "=v"(r.u[0]) : "v"(a.x), "v"(a.y));
  asm("v_cvt_pk_bf16_f32 %0, %1, %2" : "=v"(r.u[1]) : "v"(a.z), "v"(a.w));
  asm("v_cvt_pk_bf16_f32 %0, %1, %2" : "=v"(r.u[2]) : "v"(b.x), "v"(b.y));
  asm("v_cvt_pk_bf16_f32 %0, %1, %2" : "=v"(r.u[3]) : "v"(b.z), "v"(b.w));
  return r.v;
}

// tanh-form GELU, exp-based
__device__ inline float gelu_t(float v) {
  float t = 0.7978845608028654f * fmaf(0.044715f * v * v, v, v);
  t = fminf(fmaxf(t, -9.f), 9.f);
  float e = __expf(-2.f * t);
  float th = (1.f - e) * __builtin_amdgcn_rcpf(1.f + e);
  return 0.5f * v * (1.f + th);
}

__device__ inline void gload_lds16(const ushort* g, ushort* l) {
  __builtin_amdgcn_global_load_lds(
      (const __attribute__((address_space(1))) void*)g,
      (__attribute__((address_space(3))) void*)l, 16, 0, 0);
}

// ---- Pre-pack Wcat[512,544] into bf16 MFMA fragment order:
// P[ks][t][lane][j] = Wcat[k=ks*32+(l>>4)*8+j][n=t*16+(l&15)]
__global__ void prepack_kernel(const float* __restrict__ Wg,
                               const float* __restrict__ W1,
                               ushort* __restrict__ P) {
  int tid = blockIdx.x * 256 + threadIdx.x;
  const int total = KSTEPS * NT * 64;
  if (tid >= total) return;
  int l  = tid & 63;
  int t  = (tid >> 6) % NT;
  int ks = tid / (NT * 64);
  int n  = t * 16 + (l & 15);
  int kb = ks * 32 + (l >> 4) * 8;
  __align__(16) ushort v[8];
#pragma unroll
  for (int j = 0; j < 8; ++j) {
    int k = kb + j;
    float w;
    if (n < NEXP) {
      w = Wg[n * D_IN + k];
    } else {
      int e = (n - 32) >> 4, h = (n - 32) & 15;
      w = W1[(e * D_IN + k) * HID + h];
    }
    v[j] = f2bf(w);
  }
  *reinterpret_cast<int4*>(P + (size_t)tid * 8) = *reinterpret_cast<const int4*>(v);
}

// ---- Main fused kernel: BM=128 rows/block, 8 waves (wm 0..3 x wn 0..1).
// B double-buffered in LDS (global_load_lds), A direct global->reg, prefetched 1 kstep.
// acc = mfma(Wfrag, xfrag) -> C^T: lane&15 = batch row, (l>>4)*4+r = tile col.
__global__ __launch_bounds__(512, 2)
void moe_kernel(const float* __restrict__ x, const ushort* __restrict__ P,
                const float* __restrict__ b1, const float* __restrict__ W2,
                const float* __restrict__ b2, float* __restrict__ out) {
  __shared__ __align__(16) ushort Blds[2][NT * 512];   // 2 x 34 KiB, linear
  __shared__ float epi_o[NEXP][BM];
  __shared__ float epi_g[NEXP][BM];
  __shared__ float epi_s[BM];

  const int tid = threadIdx.x;
  const int l = tid & 63;
  const int wid = tid >> 6;
  const int wm = wid >> 1, wn = wid & 1;
  const int lane16 = l & 15, lg = l >> 4;
  const size_t rowBase = (size_t)blockIdx.x * BM;

  f32x4 acc[2][17];
#pragma unroll
  for (int f = 0; f < 2; ++f)
#pragma unroll
    for (int t = 0; t < 17; ++t) acc[f][t] = (f32x4){0.f, 0.f, 0.f, 0.f};

  // x fragment: row = rowBase + wm*32 + f*16 + lane16, k = ks*32 + lg*8 + j
  const float* xp0 = x + (rowBase + wm * 32 + lane16) * D_IN + lg * 8;
  const float* xp1 = xp0 + 16 * D_IN;

  float4 abuf[2][4];

  // ---- prologue: stage B(0), issue A(0)
#pragma unroll
  for (int tg = wid; tg < NT; tg += NW)
    gload_lds16(P + ((size_t)tg * 64 + l) * 8, &Blds[0][tg * 512]);
  abuf[0][0] = *reinterpret_cast<const float4*>(xp0);
  abuf[0][1] = *reinterpret_cast<const float4*>(xp0 + 4);
  abuf[0][2] = *reinterpret_cast<const float4*>(xp1);
  abuf[0][3] = *reinterpret_cast<const float4*>(xp1 + 4);
  asm volatile("s_waitcnt vmcnt(4)" ::: "memory");   // B(0) staged; A(0) still flying
  __builtin_amdgcn_s_barrier();
  __builtin_amdgcn_sched_barrier(0);

#pragma unroll
  for (int ks = 0; ks < KSTEPS; ++ks) {
    const int cur = ks & 1, nxt = cur ^ 1;
    if (ks < KSTEPS - 1) {
      // issue next B-stage and next A-loads (stay in flight across compute)
#pragma unroll
      for (int tg = wid; tg < NT; tg += NW)
        gload_lds16(P + ((size_t)((ks + 1) * NT + tg) * 64 + l) * 8,
                    &Blds[nxt][tg * 512]);
      abuf[nxt][0] = *reinterpret_cast<const float4*>(xp0 + (ks + 1) * 32);
      abuf[nxt][1] = *reinterpret_cast<const float4*>(xp0 + (ks + 1) * 32 + 4);
      abuf[nxt][2] = *reinterpret_cast<const float4*>(xp1 + (ks + 1) * 32);
      abuf[nxt][3] = *reinterpret_cast<const float4*>(xp1 + (ks + 1) * 32 + 4);
    }
    const bfrag a0 = cvt8(abuf[cur][0], abuf[cur][1]);
    const bfrag a1 = cvt8(abuf[cur][2], abuf[cur][3]);
#pragma unroll
    for (int t = 0; t < 17; ++t) {
      const bfrag b = *reinterpret_cast<const bfrag*>(&Blds[cur][(wn * 17 + t) * 512 + l * 8]);
      acc[0][t] = __builtin_amdgcn_mfma_f32_16x16x32_bf16(b, a0, acc[0][t], 0, 0, 0);
      acc[1][t] = __builtin_amdgcn_mfma_f32_16x16x32_bf16(b, a1, acc[1][t], 0, 0, 0);
    }
    if (ks < KSTEPS - 1) {
      asm volatile("s_waitcnt vmcnt(4)" ::: "memory");  // next B staged; 4 A-loads fly on
      __builtin_amdgcn_s_barrier();
      __builtin_amdgcn_sched_barrier(0);
    }
  }

  // ---- epilogue: C^T layout, lane16 = row (within 16-group), lg*4+r = tile col
  const int row0 = wm * 32 + lane16;

  if (wn == 0) {
    // gating softmax (tiles 0,1)
#pragma unroll
    for (int f = 0; f < 2; ++f) {
      const int row = row0 + f * 16;
      float mx = fmaxf(fmaxf(fmaxf(acc[f][0][0], acc[f][0][1]), fmaxf(acc[f][0][2], acc[f][0][3])),
                       fmaxf(fmaxf(acc[f][1][0], acc[f][1][1]), fmaxf(acc[f][1][2], acc[f][1][3])));
      mx = fmaxf(mx, __shfl_xor(mx, 16));
      mx = fmaxf(mx, __shfl_xor(mx, 32));
      float sum = 0.f;
#pragma unroll
      for (int t = 0; t < 2; ++t)
#pragma unroll
        for (int r = 0; r < 4; ++r) {
          float gh = __expf(acc[f][t][r] - mx);
          sum += gh;
          epi_g[t * 16 + lg * 4 + r][row] = gh;
        }
      sum += __shfl_xor(sum, 16);
      sum += __shfl_xor(sum, 32);
      if (lg == 0) epi_s[row] = sum;
    }
    // experts 0..14 (tiles 2..16)
#pragma unroll
    for (int t = 2; t < 17; ++t) {
      const int e = t - 2;
      const float4 b1v = *reinterpret_cast<const float4*>(b1 + e * HID + lg * 4);
      const float4 w2v = *reinterpret_cast<const float4*>(W2 + e * HID + lg * 4);
      const float b2v = b2[e];
#pragma unroll
      for (int f = 0; f < 2; ++f) {
        float p = gelu_t(acc[f][t][0] + b1v.x) * w2v.x;
        p = fmaf(gelu_t(acc[f][t][1] + b1v.y), w2v.y, p);
        p = fmaf(gelu_t(acc[f][t][2] + b1v.z), w2v.z, p);
        p = fmaf(gelu_t(acc[f][t][3] + b1v.w), w2v.w, p);
        p += __shfl_xor(p, 16);
        p += __shfl_xor(p, 32);
        if (lg == (t & 3)) epi_o[e][row0 + f * 16] = p + b2v;
      }
    }
  } else {
    // experts 15..31 (tiles 0..16)
#pragma unroll
    for (int t = 0; t < 17; ++t) {
      const int e = t + 15;
      const float4 b1v = *reinterpret_cast<const float4*>(b1 + e * HID + lg * 4);
      const float4 w2v = *reinterpret_cast<const float4*>(W2 + e * HID + lg * 4);
      const float b2v = b2[e];
#pragma unroll
      for (int f = 0; f < 2; ++f) {
        float p = gelu_t(acc[f][t][0] + b1v.x) * w2v.x;
        p = fmaf(gelu_t(acc[f][t][1] + b1v.y), w2v.y, p);
        p = fmaf(gelu_t(acc[f][t][2] + b1v.z), w2v.z, p);
        p = fmaf(gelu_t(acc[f][t][3] + b1v.w), w2v.w, p);
        p += __shfl_xor(p, 16);
        p += __shfl_xor(p, 32);
        if (lg == (t & 3)) epi_o[e][row0 + f * 16] = p + b2v;
      }
    }
  }

  __syncthreads();
  if (tid < BM) {
    float a = 0.f;
#pragma unroll
    for (int e = 0; e < NEXP; ++e)
      a = fmaf(epi_o[e][tid], epi_g[e][tid], a);
    out[rowBase + tid] = a / epi_s[tid];
  }
}

extern "C" void kernel_launch(void* const* d_in, const int* in_sizes, int n_in,
                              void* d_out, int out_size, void* d_ws, size_t ws_size,
                              hipStream_t stream) {
  const float* x  = (const float*)d_in[0];
  const float* Wg = (const float*)d_in[1];
  const float* W1 = (const float*)d_in[2];
  const float* b1 = (const float*)d_in[3];
  const float* W2 = (const float*)d_in[4];
  const float* b2 = (const float*)d_in[5];
  float* out = (float*)d_out;
  ushort* P = (ushort*)d_ws;   // 16*34*64*8*2 = 557,056 B

  hipLaunchKernelGGL(prepack_kernel, dim3((KSTEPS * NT * 64 + 255) / 256), dim3(256),
                     0, stream, Wg, W1, P);
  hipLaunchKernelGGL(moe_kernel, dim3(BATCH / BM), dim3(512),
                     0, stream, x, P, b1, W2, b2, out);
}

// Round 4
// 320.212 us; speedup vs baseline: 2.9702x; 1.0292x over previous
//
#include <hip/hip_runtime.h>
#include <hip/hip_bf16.h>

#define D_IN 512
#define NEXP 32
#define HID 16
#define NT 34            // 544 cols / 16
#define KSTEPS 16        // 512 / 32
#define BM 128
#define NW 8             // waves per block
#define BATCH 262144
#define LDGX 129         // padded row stride for gate-exchange LDS

typedef __attribute__((ext_vector_type(8))) short bfrag;   // 8 x bf16
typedef __attribute__((ext_vector_type(4))) float f32x4;

__device__ inline ushort f2bf(float f) {
  uint32_t u = __float_as_uint(f);
  u += 0x7fffu + ((u >> 16) & 1u);      // RNE, finite inputs
  return (ushort)(u >> 16);
}

// pack 8 fp32 -> 8 bf16 (RNE) with v_cvt_pk_bf16_f32
__device__ inline bfrag cvt8(const float4 a, const float4 b) {
  union { bfrag v; uint u[4]; } r;
  asm("v_cvt_pk_bf16_f32 %0, %1, %2" : "=v"(r.u[0]) : "v"(a.x), "v"(a.y));
  asm("v_cvt_pk_bf16_f32 %0, %1, %2" : "=v"(r.u[1]) : "v"(a.z), "v"(a.w));
  asm("v_cvt_pk_bf16_f32 %0, %1, %2" : "=v"(r.u[2]) : "v"(b.x), "v"(b.y));
  asm("v_cvt_pk_bf16_f32 %0, %1, %2" : "=v"(r.u[3]) : "v"(b.z), "v"(b.w));
  return r.v;
}

// tanh-form GELU, exp-based
__device__ inline float gelu_t(float v) {
  float t = 0.7978845608028654f * fmaf(0.044715f * v * v, v, v);
  t = fminf(fmaxf(t, -9.f), 9.f);
  float e = __expf(-2.f * t);
  float th = (1.f - e) * __builtin_amdgcn_rcpf(1.f + e);
  return 0.5f * v * (1.f + th);
}

__device__ inline void gload_lds16(const ushort* g, ushort* l) {
  __builtin_amdgcn_global_load_lds(
      (const __attribute__((address_space(1))) void*)g,
      (__attribute__((address_space(3))) void*)l, 16, 0, 0);
}

// ---- Pre-pack Wcat[512,544] into bf16 MFMA fragment order:
// P[ks][t][lane][j] = Wcat[k=ks*32+(l>>4)*8+j][n=t*16+(l&15)]
__global__ void prepack_kernel(const float* __restrict__ Wg,
                               const float* __restrict__ W1,
                               ushort* __restrict__ P) {
  int tid = blockIdx.x * 256 + threadIdx.x;
  const int total = KSTEPS * NT * 64;
  if (tid >= total) return;
  int l  = tid & 63;
  int t  = (tid >> 6) % NT;
  int ks = tid / (NT * 64);
  int n  = t * 16 + (l & 15);
  int kb = ks * 32 + (l >> 4) * 8;
  __align__(16) ushort v[8];
#pragma unroll
  for (int j = 0; j < 8; ++j) {
    int k = kb + j;
    float w;
    if (n < NEXP) {
      w = Wg[n * D_IN + k];
    } else {
      int e = (n - 32) >> 4, h = (n - 32) & 15;
      w = W1[(e * D_IN + k) * HID + h];
    }
    v[j] = f2bf(w);
  }
  *reinterpret_cast<int4*>(P + (size_t)tid * 8) = *reinterpret_cast<const int4*>(v);
}

// ---- Main fused kernel: BM=128 rows/block, 8 waves (wm 0..3 x wn 0..1).
// B double-buffered in LDS (global_load_lds), A direct global->reg, prefetched 1 kstep.
// acc = mfma(Wfrag, xfrag) -> C^T: lane&15 = batch row, (l>>4)*4+r = tile col.
// Epilogue: wn0 owns gating + experts 0..14 (in-register), exchanges 17 gates +
// partial0 + denom via 9.8 KB LDS; wn1 owns experts 15..31 + final combine.
__global__ __launch_bounds__(512, 2)
void moe_kernel(const float* __restrict__ x, const ushort* __restrict__ P,
                const float* __restrict__ b1, const float* __restrict__ W2,
                const float* __restrict__ b2, float* __restrict__ out) {
  __shared__ __align__(16) ushort Blds[2][NT * 512];   // 2 x 34 KiB, linear
  __shared__ float gxl[17 * LDGX];   // gates e=15..31 per row
  __shared__ float p0l[BM];          // wn0 partial sum per row
  __shared__ float sl[BM];           // softmax denom per row

  const int tid = threadIdx.x;
  const int l = tid & 63;
  const int wid = tid >> 6;
  const int wm = wid >> 1, wn = wid & 1;
  const int lane16 = l & 15, lg = l >> 4;
  const size_t rowBase = (size_t)blockIdx.x * BM;

  f32x4 acc[2][17];
#pragma unroll
  for (int f = 0; f < 2; ++f)
#pragma unroll
    for (int t = 0; t < 17; ++t) acc[f][t] = (f32x4){0.f, 0.f, 0.f, 0.f};

  // x fragment: row = rowBase + wm*32 + f*16 + lane16, k = ks*32 + lg*8 + j
  const float* xp0 = x + (rowBase + wm * 32 + lane16) * D_IN + lg * 8;
  const float* xp1 = xp0 + 16 * D_IN;

  float4 abuf[2][4];

  // ---- prologue: stage B(0), issue A(0)
#pragma unroll
  for (int tg = wid; tg < NT; tg += NW)
    gload_lds16(P + ((size_t)tg * 64 + l) * 8, &Blds[0][tg * 512]);
  abuf[0][0] = *reinterpret_cast<const float4*>(xp0);
  abuf[0][1] = *reinterpret_cast<const float4*>(xp0 + 4);
  abuf[0][2] = *reinterpret_cast<const float4*>(xp1);
  abuf[0][3] = *reinterpret_cast<const float4*>(xp1 + 4);
  asm volatile("s_waitcnt vmcnt(4)" ::: "memory");   // B(0) staged; A(0) still flying
  __builtin_amdgcn_s_barrier();
  __builtin_amdgcn_sched_barrier(0);

#pragma unroll
  for (int ks = 0; ks < KSTEPS; ++ks) {
    const int cur = ks & 1, nxt = cur ^ 1;
    if (ks < KSTEPS - 1) {
      // issue next B-stage and next A-loads (stay in flight across compute)
#pragma unroll
      for (int tg = wid; tg < NT; tg += NW)
        gload_lds16(P + ((size_t)((ks + 1) * NT + tg) * 64 + l) * 8,
                    &Blds[nxt][tg * 512]);
      abuf[nxt][0] = *reinterpret_cast<const float4*>(xp0 + (ks + 1) * 32);
      abuf[nxt][1] = *reinterpret_cast<const float4*>(xp0 + (ks + 1) * 32 + 4);
      abuf[nxt][2] = *reinterpret_cast<const float4*>(xp1 + (ks + 1) * 32);
      abuf[nxt][3] = *reinterpret_cast<const float4*>(xp1 + (ks + 1) * 32 + 4);
    }
    const bfrag a0 = cvt8(abuf[cur][0], abuf[cur][1]);
    const bfrag a1 = cvt8(abuf[cur][2], abuf[cur][3]);
#pragma unroll
    for (int t = 0; t < 17; ++t) {
      const bfrag b = *reinterpret_cast<const bfrag*>(&Blds[cur][(wn * 17 + t) * 512 + l * 8]);
      acc[0][t] = __builtin_amdgcn_mfma_f32_16x16x32_bf16(b, a0, acc[0][t], 0, 0, 0);
      acc[1][t] = __builtin_amdgcn_mfma_f32_16x16x32_bf16(b, a1, acc[1][t], 0, 0, 0);
    }
    if (ks < KSTEPS - 1) {
      asm volatile("s_waitcnt vmcnt(4)" ::: "memory");  // next B staged; 4 A-loads fly on
      __builtin_amdgcn_s_barrier();
      __builtin_amdgcn_sched_barrier(0);
    }
  }

  // ---- epilogue: C^T layout, lane16 = row (within 16-group), lg*4+r = tile col
  const int row0 = wm * 32 + lane16;
  float oreg[17][2];   // wn1: expert outputs, static-indexed

  if (wn == 0) {
    float gh[2][8];    // gate exps: [f][t*4+r], expert e = t*16 + lg*4 + r
    float pac[2] = {0.f, 0.f};
#pragma unroll
    for (int f = 0; f < 2; ++f) {
      const int row = row0 + f * 16;
      float mx = fmaxf(fmaxf(fmaxf(acc[f][0][0], acc[f][0][1]), fmaxf(acc[f][0][2], acc[f][0][3])),
                       fmaxf(fmaxf(acc[f][1][0], acc[f][1][1]), fmaxf(acc[f][1][2], acc[f][1][3])));
      mx = fmaxf(mx, __shfl_xor(mx, 16));
      mx = fmaxf(mx, __shfl_xor(mx, 32));
      float sum = 0.f;
#pragma unroll
      for (int t = 0; t < 2; ++t)
#pragma unroll
        for (int r = 0; r < 4; ++r) {
          float g = __expf(acc[f][t][r] - mx);
          gh[f][t * 4 + r] = g;
          sum += g;
        }
      sum += __shfl_xor(sum, 16);
      sum += __shfl_xor(sum, 32);
      if (lg == 0) sl[row] = sum;
      // export gates for experts 15..31
      if (lg == 3) gxl[row] = gh[f][3];                      // e=15 (t=0,lg=3,r=3)
#pragma unroll
      for (int r = 0; r < 4; ++r)
        gxl[(1 + lg * 4 + r) * LDGX + row] = gh[f][4 + r];   // e=16+lg*4+r
    }
    // experts 0..14 (tiles 2..16): owner-lane accumulate with in-register gates
#pragma unroll
    for (int t = 2; t < 17; ++t) {
      const int e = t - 2;
      const float4 b1v = *reinterpret_cast<const float4*>(b1 + e * HID + lg * 4);
      const float4 w2v = *reinterpret_cast<const float4*>(W2 + e * HID + lg * 4);
      const float b2v = b2[e];
#pragma unroll
      for (int f = 0; f < 2; ++f) {
        float p = gelu_t(acc[f][t][0] + b1v.x) * w2v.x;
        p = fmaf(gelu_t(acc[f][t][1] + b1v.y), w2v.y, p);
        p = fmaf(gelu_t(acc[f][t][2] + b1v.z), w2v.z, p);
        p = fmaf(gelu_t(acc[f][t][3] + b1v.w), w2v.w, p);
        p += __shfl_xor(p, 16);
        p += __shfl_xor(p, 32);                // o_e valid in all lanes
        if (lg == (e >> 2)) pac[f] = fmaf(p + b2v, gh[f][e & 3], pac[f]);
      }
    }
#pragma unroll
    for (int f = 0; f < 2; ++f) {
      float p0 = pac[f];
      p0 += __shfl_xor(p0, 16);
      p0 += __shfl_xor(p0, 32);
      if (lg == 0) p0l[row0 + f * 16] = p0;
    }
  } else {
    // experts 15..31 (tiles 0..16): keep outputs in registers
#pragma unroll
    for (int t = 0; t < 17; ++t) {
      const int e = t + 15;
      const float4 b1v = *reinterpret_cast<const float4*>(b1 + e * HID + lg * 4);
      const float4 w2v = *reinterpret_cast<const float4*>(W2 + e * HID + lg * 4);
      const float b2v = b2[e];
#pragma unroll
      for (int f = 0; f < 2; ++f) {
        float p = gelu_t(acc[f][t][0] + b1v.x) * w2v.x;
        p = fmaf(gelu_t(acc[f][t][1] + b1v.y), w2v.y, p);
        p = fmaf(gelu_t(acc[f][t][2] + b1v.z), w2v.z, p);
        p = fmaf(gelu_t(acc[f][t][3] + b1v.w), w2v.w, p);
        p += __shfl_xor(p, 16);
        p += __shfl_xor(p, 32);
        oreg[t][f] = p + b2v;
      }
    }
  }

  __syncthreads();
  if (wn == 1) {
#pragma unroll
    for (int f = 0; f < 2; ++f) {
      const int row = row0 + f * 16;
      float a = p0l[row];
#pragma unroll
      for (int t = 0; t < 17; ++t)
        a = fmaf(oreg[t][f], gxl[t * LDGX + row], a);
      if (lg == 0) out[rowBase + row] = a / sl[row];
    }
  }
}

extern "C" void kernel_launch(void* const* d_in, const int* in_sizes, int n_in,
                              void* d_out, int out_size, void* d_ws, size_t ws_size,
                              hipStream_t stream) {
  const float* x  = (const float*)d_in[0];
  const float* Wg = (const float*)d_in[1];
  const float* W1 = (const float*)d_in[2];
  const float* b1 = (const float*)d_in[3];
  const float* W2 = (const float*)d_in[4];
  const float* b2 = (const float*)d_in[5];
  float* out = (float*)d_out;
  ushort* P = (ushort*)d_ws;   // 16*34*64*8*2 = 557,056 B

  hipLaunchKernelGGL(prepack_kernel, dim3((KSTEPS * NT * 64 + 255) / 256), dim3(256),
                     0, stream, Wg, W1, P);
  hipLaunchKernelGGL(moe_kernel, dim3(BATCH / BM), dim3(512),
                     0, stream, x, P, b1, W2, b2, out);
}